// Round 1
// baseline (1145.824 us; speedup 1.0000x reference)
//
#include <hip/hip_runtime.h>
#include <hip/hip_bf16.h>

#define SDIM 2048
#define DDIM 64
#define HNUM 16
#define QT   16          // q-rows per block
#define NW   8           // waves per block
#define NT   (NW * 64)   // 512 threads

typedef __attribute__((ext_vector_type(8))) short short8;
typedef __attribute__((ext_vector_type(4))) float f32x4;

__device__ __forceinline__ short f2bf(float x) {
    union { float f; unsigned u; } c; c.f = x;
    unsigned r = (c.u + 0x7fffu + ((c.u >> 16) & 1u)) >> 16;
    return (short)(unsigned short)r;
}

__global__ __launch_bounds__(NT) void attn_fused(
    const float* __restrict__ Q, const float* __restrict__ K,
    const float* __restrict__ V, const int* __restrict__ M,
    float* __restrict__ O, float* __restrict__ W)
{
    // 128 KB swizzled fp32 score tile [QT][SDIM]
    __shared__ float4 scv[QT * (SDIM / 4)];
    float* sc = (float*)scv;
    __shared__ float rowm[QT], rowl[QT];

    const int blk = blockIdx.x;
    const int bh  = blk >> 7;          // / (SDIM/QT = 128)
    const int qt  = blk & 127;
    const int b   = bh >> 4;           // / HNUM
    const int tid = threadIdx.x;
    const int wv  = tid >> 6;
    const int ln  = tid & 63;
    const int lr  = ln & 15;
    const int lg  = ln >> 4;

    const float* Qb = Q + (size_t)bh * SDIM * DDIM + (size_t)(qt * QT) * DDIM;
    const float* Kb = K + (size_t)bh * SDIM * DDIM;
    const float* Vb = V + (size_t)bh * SDIM * DDIM;
    const int*   Mb = M + (size_t)b * SDIM * SDIM + (size_t)(qt * QT) * SDIM;
    float* Ob = O + (size_t)bh * SDIM * DDIM + (size_t)(qt * QT) * DDIM;
    float* Wb = W + (size_t)bh * SDIM * SDIM + (size_t)(qt * QT) * SDIM;

    // ---- hoisted Q A-fragments (identical across waves) ----
    // A-frag layout (16x16x32): lane l holds A[l%16][(l>>4)*8 + i]
    short8 a0, a1;
    {
        const float* qp = Qb + (size_t)lr * DDIM + lg * 8;
        #pragma unroll
        for (int i = 0; i < 8; ++i) { a0[i] = f2bf(qp[i]); a1[i] = f2bf(qp[32 + i]); }
    }

    // ---- Phase 1: scores = mask ? QK^T * scale : -inf  -> LDS (swizzled) ----
    for (int it = 0; it < SDIM / (NW * 16); ++it) {
        const int kb = it * (NW * 16) + wv * 16;   // this wave's 16 k-cols
        // B-frag: lane l holds B[(l>>4)*8+i][l%16] = K[kb + l%16][(l>>4)*8+i]
        const float* kp = Kb + (size_t)(kb + lr) * DDIM + lg * 8;
        short8 b0, b1;
        #pragma unroll
        for (int i = 0; i < 8; ++i) { b0[i] = f2bf(kp[i]); b1[i] = f2bf(kp[32 + i]); }
        f32x4 acc = {0.f, 0.f, 0.f, 0.f};
        acc = __builtin_amdgcn_mfma_f32_16x16x32_bf16(a0, b0, acc, 0, 0, 0);
        acc = __builtin_amdgcn_mfma_f32_16x16x32_bf16(a1, b1, acc, 0, 0, 0);
        // C/D layout: col = lane&15 (k), row = (lane>>4)*4 + r (q)
        const int kc = kb + lr;
        #pragma unroll
        for (int r = 0; r < 4; ++r) {
            const int q  = lg * 4 + r;
            const int mv = Mb[q * SDIM + kc];
            const float s = mv ? acc[r] * 0.125f : -INFINITY;
            sc[q * SDIM + (kc ^ ((q & 7) << 2))] = s;   // XOR swizzle on k bits 2..4
        }
    }
    __syncthreads();

    // ---- Phase 2: per-row max + sum(exp) (wave-parallel, order-free reads) ----
    for (int rr = 0; rr < QT / NW; ++rr) {
        const int q = wv * (QT / NW) + rr;
        const float4* rp = scv + q * (SDIM / 4);
        float m = -INFINITY;
        float4 v[8];
        #pragma unroll
        for (int i = 0; i < 8; ++i) {
            v[i] = rp[ln + i * 64];
            m = fmaxf(m, fmaxf(fmaxf(v[i].x, v[i].y), fmaxf(v[i].z, v[i].w)));
        }
        #pragma unroll
        for (int o = 32; o; o >>= 1) m = fmaxf(m, __shfl_xor(m, o));
        float ls = 0.f;
        #pragma unroll
        for (int i = 0; i < 8; ++i)
            ls += __expf(v[i].x - m) + __expf(v[i].y - m) +
                  __expf(v[i].z - m) + __expf(v[i].w - m);
        #pragma unroll
        for (int o = 32; o; o >>= 1) ls += __shfl_xor(ls, o);
        if (ln == 0) { rowm[q] = m; rowl[q] = 1.f / ls; }
    }
    __syncthreads();

    // ---- Phase 3: normalize+write weights, PV MFMA (wave owns 256-wide K slice) ----
    f32x4 acc[4] = {{0.f,0.f,0.f,0.f},{0.f,0.f,0.f,0.f},
                    {0.f,0.f,0.f,0.f},{0.f,0.f,0.f,0.f}};
    const int row = lr;                 // A-row (q) and B-col (d) lane index
    const float m  = rowm[row];
    const float rl = rowl[row];
    const int   x  = row & 7;
    const int   k0 = wv * (SDIM / NW);  // 256-wide slice
    for (int st = 0; st < (SDIM / NW) / 32; ++st) {
        const int kb = k0 + st * 32;
        const int s0 = (kb >> 2) + 2 * lg;          // logical 16B slot
        float4 lo = scv[row * (SDIM / 4) + ((s0)     ^ x)];
        float4 hi = scv[row * (SDIM / 4) + ((s0 + 1) ^ x)];
        const float w0 = __expf(lo.x - m) * rl;
        const float w1 = __expf(lo.y - m) * rl;
        const float w2 = __expf(lo.z - m) * rl;
        const float w3 = __expf(lo.w - m) * rl;
        const float w4 = __expf(hi.x - m) * rl;
        const float w5 = __expf(hi.y - m) * rl;
        const float w6 = __expf(hi.z - m) * rl;
        const float w7 = __expf(hi.w - m) * rl;
        // write fp32 attention weights (each element exactly once per block)
        float4 wa; wa.x = w0; wa.y = w1; wa.z = w2; wa.w = w3;
        float4 wc; wc.x = w4; wc.y = w5; wc.z = w6; wc.w = w7;
        float4* wp = reinterpret_cast<float4*>(Wb + (size_t)row * SDIM + kb + lg * 8);
        wp[0] = wa; wp[1] = wc;
        // A-frag for PV
        short8 af;
        af[0] = f2bf(w0); af[1] = f2bf(w1); af[2] = f2bf(w2); af[3] = f2bf(w3);
        af[4] = f2bf(w4); af[5] = f2bf(w5); af[6] = f2bf(w6); af[7] = f2bf(w7);
        // B-frags: B[k][n] = V[kb+lg*8+i][nb*16 + l%16]
        const float* vp = Vb + (size_t)(kb + lg * 8) * DDIM + lr;
        #pragma unroll
        for (int nb = 0; nb < 4; ++nb) {
            short8 bf;
            #pragma unroll
            for (int i = 0; i < 8; ++i) bf[i] = f2bf(vp[i * DDIM + nb * 16]);
            acc[nb] = __builtin_amdgcn_mfma_f32_16x16x32_bf16(af, bf, acc[nb], 0, 0, 0);
        }
    }
    __syncthreads();   // all waves done reading sc before reuse

    // ---- Phase 4: cross-wave reduction of partial PV tiles via LDS ----
    float* part = (float*)scv;   // [NW][QT][DDIM] = 32 KB
    #pragma unroll
    for (int nb = 0; nb < 4; ++nb)
        #pragma unroll
        for (int r = 0; r < 4; ++r)
            part[wv * QT * DDIM + (lg * 4 + r) * DDIM + nb * 16 + lr] = acc[nb][r];
    __syncthreads();
    for (int e = tid; e < QT * DDIM; e += NT) {
        float s = 0.f;
        #pragma unroll
        for (int w = 0; w < NW; ++w) s += part[w * QT * DDIM + e];
        Ob[e] = s;
    }
}

extern "C" void kernel_launch(void* const* d_in, const int* in_sizes, int n_in,
                              void* d_out, int out_size, void* d_ws, size_t ws_size,
                              hipStream_t stream) {
    const float* Q = (const float*)d_in[0];
    const float* K = (const float*)d_in[1];
    const float* V = (const float*)d_in[2];
    const int*   M = (const int*)d_in[3];
    float* O = (float*)d_out;
    float* W = O + (size_t)4 * HNUM * SDIM * DDIM;   // out0 first, then attn_weights
    dim3 grid(4 * HNUM * (SDIM / QT));               // 8192 blocks
    attn_fused<<<grid, NT, 0, stream>>>(Q, K, V, M, O, W);
}

// Round 2
// 763.667 us; speedup vs baseline: 1.5004x; 1.5004x over previous
//
#include <hip/hip_runtime.h>
#include <hip/hip_bf16.h>

#define SEQ  2048
#define DH   64
#define NBH  64          // B*H
#define NH   16
#define QT   16          // q-rows per block
#define NW   8           // waves per block
#define NT   (NW * 64)

typedef __attribute__((ext_vector_type(8))) short short8;
typedef __attribute__((ext_vector_type(4))) float f32x4;

__device__ __forceinline__ unsigned short f2bf(float x) {
    union { float f; unsigned u; } c; c.f = x;
    return (unsigned short)((c.u + 0x7fffu + ((c.u >> 16) & 1u)) >> 16);
}
__device__ __forceinline__ unsigned pk2(float a, float b) {
    return (unsigned)f2bf(a) | ((unsigned)f2bf(b) << 16);
}

// ---- prepass: Q,K fp32 -> bf16 (same layout) ----
__global__ void prep_qk(const float* __restrict__ Q, const float* __restrict__ K,
                        unsigned short* __restrict__ Qb, unsigned short* __restrict__ Kb) {
    unsigned i4 = blockIdx.x * 256u + threadIdx.x;
    const float* src; unsigned short* dst;
    if (i4 < 2097152u) { src = Q; dst = Qb; }
    else { i4 -= 2097152u; src = K; dst = Kb; }
    float4 v = ((const float4*)src)[i4];
    ushort4 o; o.x = f2bf(v.x); o.y = f2bf(v.y); o.z = f2bf(v.z); o.w = f2bf(v.w);
    ((ushort4*)dst)[i4] = o;
}

// ---- prepass: V fp32 [bh][s][d] -> bf16 transposed [bh][d][s] ----
__global__ void prep_v(const float* __restrict__ V, unsigned short* __restrict__ VT) {
    __shared__ unsigned short tile[64][72];
    const int t = threadIdx.x;
    const int bh = blockIdx.x >> 5;
    const int s0 = (blockIdx.x & 31) * 64;
    const float* vb = V + ((size_t)bh * SEQ + s0) * DH;
    #pragma unroll
    for (int pp = 0; pp < 4; ++pp) {
        const int sr = pp * 16 + (t >> 4);
        const int dc = (t & 15) * 4;
        float4 v = *(const float4*)(vb + sr * DH + dc);
        tile[sr][dc]     = f2bf(v.x); tile[sr][dc + 1] = f2bf(v.y);
        tile[sr][dc + 2] = f2bf(v.z); tile[sr][dc + 3] = f2bf(v.w);
    }
    __syncthreads();
    const int d = t >> 2, c = (t & 3) * 16;
    short8 w0, w1;
    #pragma unroll
    for (int j = 0; j < 8; ++j) { w0[j] = (short)tile[c + j][d]; w1[j] = (short)tile[c + 8 + j][d]; }
    unsigned short* o = VT + ((size_t)bh * DH + d) * SEQ + s0 + c;
    *(short8*)o = w0; *(short8*)(o + 8) = w1;
}

// ---- prepass: mask int32 -> byte ----
__global__ void prep_m(const int* __restrict__ M, unsigned char* __restrict__ M8) {
    const unsigned i4 = blockIdx.x * 256u + threadIdx.x;
    int4 m = ((const int4*)M)[i4];
    uchar4 o; o.x = (unsigned char)(m.x != 0); o.y = (unsigned char)(m.y != 0);
    o.z = (unsigned char)(m.z != 0); o.w = (unsigned char)(m.w != 0);
    ((uchar4*)M8)[i4] = o;
}

template<bool PRE>
__global__ __launch_bounds__(NT, 4) void attn_main(
    const float* __restrict__ Qf, const float* __restrict__ Kf,
    const float* __restrict__ Vf, const int* __restrict__ Mi,
    const unsigned short* __restrict__ Qb, const unsigned short* __restrict__ Kb,
    const unsigned short* __restrict__ VT, const unsigned char* __restrict__ M8,
    float* __restrict__ O, float* __restrict__ W)
{
    __shared__ float lds[NW * 16 * 132];            // 67.5 KB: P tiles, later O partials
    __shared__ float redm[NW * 16], reds[NW * 16], rowRL[16];

    const int tid = threadIdx.x, wv = tid >> 6, ln = tid & 63;
    const int lr = ln & 15, lg = ln >> 4;
    const int h = blockIdx.x & 15, t2 = blockIdx.x >> 4;
    const int qt = t2 & 127, b = t2 >> 7;
    const int bh = b * NH + h, q0 = qt * QT, k0 = wv * (SEQ / NW);

    // ---- Q as MFMA B-fragment (swapped QK^T): lane holds Q[q0+lr][8lg+i] ----
    short8 qf0, qf1;
    if (PRE) {
        const unsigned short* qp = Qb + ((size_t)bh * SEQ + q0 + lr) * DH + 8 * lg;
        qf0 = *(const short8*)qp; qf1 = *(const short8*)(qp + 32);
    } else {
        const float* qp = Qf + ((size_t)bh * SEQ + q0 + lr) * DH + 8 * lg;
        #pragma unroll
        for (int i = 0; i < 8; ++i) { qf0[i] = (short)f2bf(qp[i]); qf1[i] = (short)f2bf(qp[32 + i]); }
    }

    // ---- scores in registers: p[kt][r] = P[q=lr][k = k0 + 16kt + 4lg + r] ----
    f32x4 p[16];
    #pragma unroll
    for (int kt = 0; kt < 16; ++kt) {
        short8 ka0, ka1;
        if (PRE) {
            const unsigned short* kp = Kb + ((size_t)bh * SEQ + k0 + kt * 16 + lr) * DH + 8 * lg;
            ka0 = *(const short8*)kp; ka1 = *(const short8*)(kp + 32);
        } else {
            const float* kp = Kf + ((size_t)bh * SEQ + k0 + kt * 16 + lr) * DH + 8 * lg;
            #pragma unroll
            for (int i = 0; i < 8; ++i) { ka0[i] = (short)f2bf(kp[i]); ka1[i] = (short)f2bf(kp[32 + i]); }
        }
        f32x4 a = {0.f, 0.f, 0.f, 0.f};
        a = __builtin_amdgcn_mfma_f32_16x16x32_bf16(ka0, qf0, a, 0, 0, 0);
        a = __builtin_amdgcn_mfma_f32_16x16x32_bf16(ka1, qf1, a, 0, 0, 0);
        int m0, m1, m2, m3;
        if (PRE) {
            uchar4 mv = *(const uchar4*)(M8 + (size_t)b * SEQ * SEQ + (size_t)(q0 + lr) * SEQ + k0 + kt * 16 + 4 * lg);
            m0 = mv.x; m1 = mv.y; m2 = mv.z; m3 = mv.w;
        } else {
            int4 mv = *(const int4*)(Mi + (size_t)b * SEQ * SEQ + (size_t)(q0 + lr) * SEQ + k0 + kt * 16 + 4 * lg);
            m0 = mv.x; m1 = mv.y; m2 = mv.z; m3 = mv.w;
        }
        p[kt][0] = m0 ? a[0] * 0.125f : -INFINITY;
        p[kt][1] = m1 ? a[1] * 0.125f : -INFINITY;
        p[kt][2] = m2 ? a[2] * 0.125f : -INFINITY;
        p[kt][3] = m3 ? a[3] * 0.125f : -INFINITY;
    }

    // ---- row max: in-lane + shfl over lg + cross-wave LDS ----
    float m = -INFINITY;
    #pragma unroll
    for (int kt = 0; kt < 16; ++kt)
        m = fmaxf(m, fmaxf(fmaxf(p[kt][0], p[kt][1]), fmaxf(p[kt][2], p[kt][3])));
    m = fmaxf(m, __shfl_xor(m, 16));
    m = fmaxf(m, __shfl_xor(m, 32));
    if (ln < 16) redm[wv * 16 + ln] = m;
    __syncthreads();
    float mf = redm[lr];
    #pragma unroll
    for (int w = 1; w < NW; ++w) mf = fmaxf(mf, redm[w * 16 + lr]);

    // ---- exp + row sum ----
    float ls = 0.f;
    #pragma unroll
    for (int kt = 0; kt < 16; ++kt) {
        #pragma unroll
        for (int r = 0; r < 4; ++r) { float e = __expf(p[kt][r] - mf); p[kt][r] = e; ls += e; }
    }
    ls += __shfl_xor(ls, 16);
    ls += __shfl_xor(ls, 32);
    if (ln < 16) reds[wv * 16 + ln] = ls;
    __syncthreads();
    float l = reds[lr];
    #pragma unroll
    for (int w = 1; w < NW; ++w) l += reds[w * 16 + lr];
    const float rl = 1.f / l;
    if (wv == 0 && ln < 16) rowRL[ln] = rl;

    // ---- W write (normalized, float4) + P bf16 pack into LDS [16 q][132 dw] ----
    float* Wp = W + (size_t)bh * SEQ * SEQ + (size_t)(q0 + lr) * SEQ + k0 + 4 * lg;
    unsigned* ldsU = (unsigned*)lds;
    unsigned* pb = ldsU + wv * 2112 + lr * 132 + 2 * lg;
    #pragma unroll
    for (int kt = 0; kt < 16; ++kt) {
        float4 w4; w4.x = p[kt][0] * rl; w4.y = p[kt][1] * rl;
        w4.z = p[kt][2] * rl; w4.w = p[kt][3] * rl;
        *(float4*)(Wp + kt * 16) = w4;
        uint2 pk; pk.x = pk2(p[kt][0], p[kt][1]); pk.y = pk2(p[kt][2], p[kt][3]);
        *(uint2*)(pb + kt * 8) = pk;                // ds_write_b64, bank-minimum
    }

    // ---- PV over this wave's 256-k slice (unnormalized P; scale O at end) ----
    f32x4 oa[4] = {{0.f,0.f,0.f,0.f},{0.f,0.f,0.f,0.f},{0.f,0.f,0.f,0.f},{0.f,0.f,0.f,0.f}};
    const unsigned* ab = ldsU + wv * 2112 + lr * 132 + 4 * lg;
    #pragma unroll
    for (int s = 0; s < 8; ++s) {
        short8 af = *(const short8*)(ab + 16 * s);  // ds_read_b128, conflict-free
        if (PRE) {
            const unsigned short* vp = VT + (size_t)bh * DH * SEQ + k0 + 32 * s + 8 * lg;
            #pragma unroll
            for (int nb = 0; nb < 4; ++nb) {
                short8 bf = *(const short8*)(vp + (size_t)(nb * 16 + lr) * SEQ);
                oa[nb] = __builtin_amdgcn_mfma_f32_16x16x32_bf16(af, bf, oa[nb], 0, 0, 0);
            }
        } else {
            const float* vp = Vf + ((size_t)bh * SEQ + k0 + 32 * s + 8 * lg) * DH + lr;
            #pragma unroll
            for (int nb = 0; nb < 4; ++nb) {
                short8 bf;
                #pragma unroll
                for (int i = 0; i < 8; ++i) bf[i] = (short)f2bf(vp[i * DH + nb * 16]);
                oa[nb] = __builtin_amdgcn_mfma_f32_16x16x32_bf16(af, bf, oa[nb], 0, 0, 0);
            }
        }
    }

    // ---- cross-wave O reduction (reuse lds; padded stride 65) ----
    __syncthreads();
    #pragma unroll
    for (int nb = 0; nb < 4; ++nb)
        #pragma unroll
        for (int r = 0; r < 4; ++r)
            lds[wv * 1040 + (4 * lg + r) * 65 + nb * 16 + lr] = oa[nb][r];
    __syncthreads();
    float* Ob = O + ((size_t)bh * SEQ + q0) * DH;
    for (int e = tid; e < QT * DH; e += NT) {
        const int q = e >> 6, d = e & 63;
        float sacc = 0.f;
        #pragma unroll
        for (int w = 0; w < NW; ++w) sacc += lds[w * 1040 + q * 65 + d];
        Ob[e] = sacc * rowRL[q];
    }
}

extern "C" void kernel_launch(void* const* d_in, const int* in_sizes, int n_in,
                              void* d_out, int out_size, void* d_ws, size_t ws_size,
                              hipStream_t stream) {
    const float* Q = (const float*)d_in[0];
    const float* K = (const float*)d_in[1];
    const float* V = (const float*)d_in[2];
    const int*   M = (const int*)d_in[3];
    float* O = (float*)d_out;
    float* W = O + (size_t)NBH * SEQ * DH;

    const bool pre = ws_size >= (size_t)67108864;   // 64 MiB scratch layout
    unsigned short* Qb = (unsigned short*)d_ws;
    unsigned short* Kb = Qb + (size_t)8388608;
    unsigned short* VT = Qb + (size_t)2 * 8388608;
    unsigned char*  M8 = (unsigned char*)(Qb + (size_t)3 * 8388608);

    if (pre) {
        prep_qk<<<16384, 256, 0, stream>>>(Q, K, Qb, Kb);
        prep_v<<<2048, 256, 0, stream>>>(V, VT);
        prep_m<<<16384, 256, 0, stream>>>(M, M8);
        attn_main<true><<<8192, NT, 0, stream>>>(Q, K, V, M, Qb, Kb, VT, M8, O, W);
    } else {
        attn_main<false><<<8192, NT, 0, stream>>>(Q, K, V, M, nullptr, nullptr, nullptr, nullptr, O, W);
    }
}